// Round 4
// baseline (220.482 us; speedup 1.0000x reference)
//
#include <hip/hip_runtime.h>
#include <stdint.h>

// Problem: x (32,128,8192) f32, weight (128,128,1,2) f32
// out[b,o,p] = sum_{c,k} x[b,c,2p+k] * w[o,c,k] / sqrt(128),  out (32,128,4096) f32
// GEMM: M=(b,p)=131072, N=o=128, K=(c,k)=256. HBM-bound with bf16 MFMA.
//
// R4: single fused kernel. R3's two-kernel d_ws write->read handoff was
// intermittently stale (cross-XCD visibility + 512MB d_ws re-poison race):
// first launch passed, a later fresh launch read poison -> absmax 2.19.
// Fix: each block converts the read-only 128 KB fp32 weight (d_in[1]) into
// bf16 B-fragment layout in its own LDS. No d_ws, no inter-kernel dependency.
// Keeps R3's vmcnt decoupling: B reads are ds_read_b128 (lgkmcnt domain),
// vmcnt carries ONLY the A stream (distance-2 prefetch, steady wait vmcnt(4)).

typedef __attribute__((ext_vector_type(8))) short bf16x8;   // 8 bf16 = 4 VGPRs
typedef __attribute__((ext_vector_type(4))) float f32x4;    // MFMA C/D

#define CIN  128
#define DLEN 8192
#define PLEN 4096
#define COUT 128

// pack two fp32 -> bf16x2 (RTNE), lo = a, hi = b
__device__ inline unsigned pack_bf(float a, float b) {
    unsigned ua = __builtin_bit_cast(unsigned, a);
    unsigned ub = __builtin_bit_cast(unsigned, b);
    unsigned ra = ua + 0x7FFFu + ((ua >> 16) & 1u);
    unsigned rb = ub + 0x7FFFu + ((ub >> 16) & 1u);
    return (ra >> 16) | (rb & 0xFFFF0000u);
}

// One block = 4 waves = 256 threads, 128 positions of one batch, all 128
// outputs, K=256. Wave: 32 positions interleaved across two 16x16 M-tiles
// (tile0 = even offsets, tile1 = odd) so A row loads are dwordx4 feeding both.
// B fragment layout in LDS (bf16 index): (kk>>3)*1024 + o*8 + (kk&7), kk=2c+k.
__global__ __launch_bounds__(256, 2) void conv_mfma(const float* __restrict__ x,
                                                    const float* __restrict__ w,
                                                    float* __restrict__ out) {
    __shared__ uint4 bsh4[4096];              // 64 KB: full B, fragment layout
    int tid = threadIdx.x;

    // ---- fused weight convert: fp32 w -> bf16 fragments in LDS ----
    // thread tid, iter j: src float4 w4[(tid>>1)*64 + j*2 + (tid&1)]
    //                     dst uint2 index j*256 + tid  (= bf16 idx 4*(j*256+tid))
    // Verified mapping: bf16 idx 4*D2+{0..3} <-> o=tid>>1, kk=j*8+(tid&1)*4+{0..3}.
    {
        const float4* w4 = (const float4*)w;
        uint2* bsh2 = (uint2*)bsh4;
        int o2 = tid >> 1, half = tid & 1;
        const float s = 0.088388347648318447f;  // 1/sqrt(128)
#pragma unroll
        for (int j = 0; j < 32; ++j) {
            float4 f = w4[o2 * 64 + j * 2 + half];
            uint2 v;
            v.x = pack_bf(f.x * s, f.y * s);
            v.y = pack_bf(f.z * s, f.w * s);
            bsh2[j * 256 + tid] = v;
        }
    }
    __syncthreads();
    const uint32_t* bsh = (const uint32_t*)bsh4;

    int tile = blockIdx.x;            // 0..1023
    int b    = tile >> 5;
    int pt   = (tile & 31) * 128;
    int lane = tid & 63;
    int wv   = tid >> 6;              // wave 0..3
    int quad = lane >> 4;
    int l16  = lane & 15;
    int pbase = pt + wv * 32;         // wave's 32-position strip

    // A lane base: row c = quad*4 (+jj, +16*kc), elem 2*pbase + 4*l16
    const float* xl = x + (size_t)b * ((size_t)CIN * DLEN)
                        + (size_t)(quad * 4) * DLEN + 2 * pbase + 4 * l16;

    f32x4 acc[2][8];
#pragma unroll
    for (int mt = 0; mt < 2; ++mt)
#pragma unroll
        for (int t = 0; t < 8; ++t)
            acc[mt][t] = (f32x4)(0.0f);

    // ---- A prefetch, distance 2: vmcnt carries only these ----
    float4 abuf[2][4];
#pragma unroll
    for (int jj = 0; jj < 4; ++jj)
        abuf[0][jj] = *(const float4*)(xl + (size_t)jj * DLEN);
#pragma unroll
    for (int jj = 0; jj < 4; ++jj)
        abuf[1][jj] = *(const float4*)(xl + (size_t)(16 + jj) * DLEN);

#pragma unroll
    for (int kc = 0; kc < 8; ++kc) {
        // consume A(kc): steady-state wait is vmcnt(4), A(kc+1) stays in flight
        union { bf16x8 v; unsigned uu[4]; } afr0, afr1;
#pragma unroll
        for (int jj = 0; jj < 4; ++jj) {
            float4 v = abuf[kc & 1][jj];
            afr0.uu[jj] = pack_bf(v.x, v.y);   // even positions
            afr1.uu[jj] = pack_bf(v.z, v.w);   // odd positions
        }
        // issue A(kc+2) into the freed slot
        if (kc < 6) {
            const float* nx = xl + (size_t)((kc + 2) * 16) * DLEN;
#pragma unroll
            for (int jj = 0; jj < 4; ++jj)
                abuf[kc & 1][jj] = *(const float4*)(nx + (size_t)jj * DLEN);
        }
        // B fragments from LDS (lgkmcnt domain — never touches vmcnt)
        const uint32_t* bk = bsh + (kc * 4 + quad) * 512 + l16 * 4;
#pragma unroll
        for (int t = 0; t < 8; ++t) {
            union { bf16x8 v; uint4 u; } bfr;
            bfr.u = *(const uint4*)(bk + t * 64);
            acc[0][t] = __builtin_amdgcn_mfma_f32_16x16x32_bf16(afr0.v, bfr.v, acc[0][t], 0, 0, 0);
            acc[1][t] = __builtin_amdgcn_mfma_f32_16x16x32_bf16(afr1.v, bfr.v, acc[1][t], 0, 0, 0);
        }
    }

    // ---- Epilogue: C/D row = quad*4 + reg; interleave even/odd tiles ----
    float* ob = out + (size_t)b * ((size_t)COUT * PLEN) + pbase + quad * 8;
#pragma unroll
    for (int t = 0; t < 8; ++t) {
        int o = t * 16 + l16;
        float* orow = ob + (size_t)o * PLEN;
        f32x4 v0 = { acc[0][t][0], acc[1][t][0], acc[0][t][1], acc[1][t][1] };
        f32x4 v1 = { acc[0][t][2], acc[1][t][2], acc[0][t][3], acc[1][t][3] };
        *(f32x4*)(orow)     = v0;
        *(f32x4*)(orow + 4) = v1;
    }
}

extern "C" void kernel_launch(void* const* d_in, const int* in_sizes, int n_in,
                              void* d_out, int out_size, void* d_ws, size_t ws_size,
                              hipStream_t stream) {
    const float* x = (const float*)d_in[0];
    const float* w = (const float*)d_in[1];
    float* out = (float*)d_out;
    (void)d_ws; (void)ws_size;

    conv_mfma<<<1024, 256, 0, stream>>>(x, w, out);
}